// Round 5
// baseline (247.234 us; speedup 1.0000x reference)
//
#include <hip/hip_runtime.h>

#define NS 16
#define N_ATOMS 2000
#define NB 2000
#define NA 4000
#define NV 400000
#define NT 6000
#define NI 1000

#define OUT_S 819001
#define OFF_EB 0
#define OFF_EA 2000
#define OFF_EUB 6000
#define OFF_EV 6001
#define OFF_EC 406001
#define OFF_ET 806001
#define OFF_EI 812001
#define OFF_F 813001

#define CHARGE_TENTH 1.8222615f

#define NPAIRS 200000          // NV/2
#define VBLK 256
#define PPT 16                 // pairs per thread
#define PAIRS_PER_BLK (VBLK * PPT)          // 4096
#define VBLKS ((NPAIRS + PAIRS_PER_BLK - 1) / PAIRS_PER_BLK)   // 49
#define BBLKS 2
#define NPART (VBLKS + BBLKS)  // 51
#define NBOND_TOT (NB + NA + NT + NI)       // 13000
#define BTPB ((NBOND_TOT + BBLKS - 1) / BBLKS)  // 6500

typedef __fp16 h2 __attribute__((ext_vector_type(2)));

// ---------------------------------------------------------------------------
// Kernel 1: E_ub zero + per-v vdw/charge param precompute (sample-independent).
__global__ __launch_bounds__(512) void prep_kernel(
    const float* __restrict__ v14,
    const float* __restrict__ q14,
    const float* __restrict__ pv,
    const float* __restrict__ pc,
    const int*   __restrict__ nb,
    const int*   __restrict__ nbi,
    float4* __restrict__ ws,
    float* __restrict__ out)
{
    int idx = blockIdx.x * blockDim.x + threadIdx.x;
    if (idx < NS)
        out[(size_t)idx * OUT_S + OFF_EUB] = 0.0f;
    if (idx < NV) {
        int v = idx;
        int i = nb[v];
        int j = nb[NV + v];
        float2 pvi = ((const float2*)pv)[i];
        float2 pvj = ((const float2*)pv)[j];
        float sigma = pvi.x + pvj.x;
        float sig2  = sigma * sigma;
        float sig6  = sig2 * sig2 * sig2;
        float eps   = pvi.y * pvj.y * 0.01f * v14[v];
        float cc    = (CHARGE_TENTH * CHARGE_TENTH) * pc[i] * pc[j] * q14[v];
        int2 aa = ((const int2*)nbi)[v];
        unsigned int packed = (unsigned int)aa.x | ((unsigned int)aa.y << 16);
        float4 w;
        w.x = sig6; w.y = eps; w.z = cc; w.w = __uint_as_float(packed);
        ws[v] = w;
    }
}

// ---------------------------------------------------------------------------
__device__ __forceinline__ void lds_pk_add(unsigned* base, int idx, float x, float y) {
    h2 ph = __builtin_amdgcn_cvt_pkrtz(x, y);
    unsigned pk = __builtin_bit_cast(unsigned, ph);
    unsigned addr = (unsigned)(uintptr_t)(&base[idx]);
    // no "memory" clobber: allow the scheduler to pipeline loads across these
    asm volatile("ds_pk_add_f16 %0, %1" : : "v"(addr), "v"(pk));
}

// ---------------------------------------------------------------------------
// Kernel 2: fat kernel. y < VBLKS: vdw+charge chunk; y >= VBLKS: bonded half.
// NO global atomics anywhere: per-block partial forces go to ws (plane layout
// [s][part][comp*2000 + atom]), summed later by reduce_kernel.
__global__ __launch_bounds__(VBLK, 4) void fused_kernel(
    const float*  __restrict__ lv,
    const float*  __restrict__ dlv,
    const float4* __restrict__ ws,
    float*        __restrict__ part,   // [NS][NPART][6000]
    const float* __restrict__ lb,
    const float* __restrict__ th,
    const float* __restrict__ sc,
    const float* __restrict__ c2i,
    const float* __restrict__ pb,
    const float* __restrict__ pa,
    const float* __restrict__ pt,
    const float* __restrict__ pim,
    const float* __restrict__ dlb,
    const float* __restrict__ dth,
    const float* __restrict__ dtt,
    const float* __restrict__ dc2,
    const int*   __restrict__ bidx,
    const int*   __restrict__ aidx,
    const int*   __restrict__ tidx,
    const int*   __restrict__ iidx,
    float* __restrict__ out)
{
    __shared__ float smem[N_ATOMS * 3];   // 24 KB
    int tid = threadIdx.x;
    int s   = blockIdx.x;
    int y   = blockIdx.y;
    float* outE = out + (size_t)s * OUT_S;
    float* mypart = part + ((size_t)s * NPART + y) * (N_ATOMS * 3);

    if (y >= VBLKS) {
        // ---------------- bonded path: LDS accumulate, then partial flush ----
        for (int k = tid; k < N_ATOMS * 3; k += VBLK) smem[k] = 0.0f;
        __syncthreads();
        int t0 = (y - VBLKS) * BTPB;
        for (int it = 0; it < (BTPB + VBLK - 1) / VBLK; ++it) {
            int t = t0 + it * VBLK + tid;
            if (t >= t0 + BTPB || t >= NBOND_TOT) continue;
            if (t < NB) {
                int b = t;
                float2 p = ((const float2*)pb)[b];
                float K  = p.x * 100.0f;
                float d  = lb[s * NB + b] - p.y;
                outE[OFF_EB + b] = K * d * d;
                float g = 2.0f * K * d;
                const float2* dd = (const float2*)(dlb + ((size_t)s * NB + b) * 6);
                float2 d0 = dd[0], d1 = dd[1], d2 = dd[2];
                int a0 = bidx[2 * b] * 3, a1 = bidx[2 * b + 1] * 3;
                atomicAdd(&smem[a0 + 0], d0.x * g);
                atomicAdd(&smem[a0 + 1], d0.y * g);
                atomicAdd(&smem[a0 + 2], d1.x * g);
                atomicAdd(&smem[a1 + 0], d1.y * g);
                atomicAdd(&smem[a1 + 1], d2.x * g);
                atomicAdd(&smem[a1 + 2], d2.y * g);
            } else if (t < NB + NA) {
                int a = t - NB;
                float2 p = ((const float2*)pa)[a];
                float Ka  = p.x * 10.0f;
                float da  = th[s * NA + a] - p.y * 0.31415926535f;
                outE[OFF_EA + a] = Ka * da * da;
                float g = 2.0f * Ka * da;
                const float* dd = dth + ((size_t)s * NA + a) * 9;
                int a0 = aidx[3 * a] * 3, a1 = aidx[3 * a + 1] * 3, a2 = aidx[3 * a + 2] * 3;
                #pragma unroll
                for (int c = 0; c < 3; ++c) atomicAdd(&smem[a0 + c], dd[c] * g);
                #pragma unroll
                for (int c = 0; c < 3; ++c) atomicAdd(&smem[a1 + c], dd[3 + c] * g);
                #pragma unroll
                for (int c = 0; c < 3; ++c) atomicAdd(&smem[a2 + c], dd[6 + c] * g);
            } else if (t < NB + NA + NT) {
                int tt = t - (NB + NA);
                const float4* s8 = (const float4*)(sc + ((size_t)s * NT + tt) * 8);
                float4 sA = s8[0], sB = s8[1];
                float4 p4 = ((const float4*)pt)[tt];
                float E  = sA.y * p4.x + sA.w * p4.y + sB.y * p4.z + sB.w * p4.w;
                float Sf = sA.x * p4.x + sA.z * p4.y * 2.0f + sB.x * p4.z * 3.0f + sB.z * p4.w * 4.0f;
                outE[OFF_ET + tt] = E;
                float g = -Sf;
                const float4* dd = (const float4*)(dtt + ((size_t)s * NT + tt) * 12);
                float4 dA = dd[0], dB = dd[1], dC = dd[2];
                int a0 = tidx[4 * tt] * 3, a1 = tidx[4 * tt + 1] * 3,
                    a2 = tidx[4 * tt + 2] * 3, a3 = tidx[4 * tt + 3] * 3;
                atomicAdd(&smem[a0 + 0], dA.x * g);
                atomicAdd(&smem[a0 + 1], dA.y * g);
                atomicAdd(&smem[a0 + 2], dA.z * g);
                atomicAdd(&smem[a1 + 0], dA.w * g);
                atomicAdd(&smem[a1 + 1], dB.x * g);
                atomicAdd(&smem[a1 + 2], dB.y * g);
                atomicAdd(&smem[a2 + 0], dB.z * g);
                atomicAdd(&smem[a2 + 1], dB.w * g);
                atomicAdd(&smem[a2 + 2], dC.x * g);
                atomicAdd(&smem[a3 + 0], dC.y * g);
                atomicAdd(&smem[a3 + 1], dC.z * g);
                atomicAdd(&smem[a3 + 2], dC.w * g);
            } else {
                int ii = t - (NB + NA + NT);
                float ki = pim[ii];
                outE[OFF_EI + ii] = ki * (1.0f - c2i[s * NI + ii]);
                float g = -ki;
                const float4* dd = (const float4*)(dc2 + ((size_t)s * NI + ii) * 12);
                float4 dA = dd[0], dB = dd[1], dC = dd[2];
                int a0 = iidx[4 * ii] * 3, a1 = iidx[4 * ii + 1] * 3,
                    a2 = iidx[4 * ii + 2] * 3, a3 = iidx[4 * ii + 3] * 3;
                atomicAdd(&smem[a0 + 0], dA.x * g);
                atomicAdd(&smem[a0 + 1], dA.y * g);
                atomicAdd(&smem[a0 + 2], dA.z * g);
                atomicAdd(&smem[a1 + 0], dA.w * g);
                atomicAdd(&smem[a1 + 1], dB.x * g);
                atomicAdd(&smem[a1 + 2], dB.y * g);
                atomicAdd(&smem[a2 + 0], dB.z * g);
                atomicAdd(&smem[a2 + 1], dB.w * g);
                atomicAdd(&smem[a2 + 2], dC.x * g);
                atomicAdd(&smem[a3 + 0], dC.y * g);
                atomicAdd(&smem[a3 + 1], dC.z * g);
                atomicAdd(&smem[a3 + 2], dC.w * g);
            }
        }
        __syncthreads();
        // flush interleaved LDS -> plane layout partial (coalesced writes)
        for (int k = tid; k < N_ATOMS; k += VBLK) {
            mypart[0 * N_ATOMS + k] = smem[3 * k + 0];
            mypart[1 * N_ATOMS + k] = smem[3 * k + 1];
            mypart[2 * N_ATOMS + k] = smem[3 * k + 2];
        }
        return;
    }

    // ---------------- vdw + charge path ----------------
    unsigned* fxy = (unsigned*)smem;        // [N_ATOMS] packed f16 (x,y)
    float*    fz  = smem + N_ATOMS;         // [N_ATOMS] f32 z
    for (int k = tid; k < 2 * N_ATOMS; k += VBLK) smem[k] = 0.0f;
    __syncthreads();

    const int pbase = y * PAIRS_PER_BLK;
    const int PLAST = NPAIRS - 1;
    const float2* lvp   = (const float2*)(lv + (size_t)s * NV);
    const float4* dbase = (const float4*)(dlv + (size_t)s * NV * 6);

    // prefetch iteration 0
    int pc = pbase + tid; if (pc > PLAST) pc = PLAST;
    float4 w0 = ws[2 * pc], w1 = ws[2 * pc + 1];
    float2 rr = lvp[pc];
    float4 A = dbase[3 * (size_t)pc];
    float4 B = dbase[3 * (size_t)pc + 1];
    float4 C = dbase[3 * (size_t)pc + 2];

    #pragma unroll
    for (int it = 0; it < PPT; ++it) {
        // issue next iteration's loads before processing current
        float4 w0n, w1n, An, Bn, Cn; float2 rrn;
        if (it + 1 < PPT) {
            int pn = pbase + (it + 1) * VBLK + tid; if (pn > PLAST) pn = PLAST;
            w0n = ws[2 * pn]; w1n = ws[2 * pn + 1];
            rrn = lvp[pn];
            An = dbase[3 * (size_t)pn];
            Bn = dbase[3 * (size_t)pn + 1];
            Cn = dbase[3 * (size_t)pn + 2];
        }

        int praw = pbase + it * VBLK + tid;
        float keep = (praw < NPAIRS) ? 1.0f : 0.0f;
        int p = (praw > PLAST) ? PLAST : praw;
        int v0 = 2 * p;
        // --- v0 ---
        {
            float rinv  = __builtin_amdgcn_rcpf(rr.x);
            float r2inv = rinv * rinv;
            float r6inv = r2inv * r2inv * r2inv;
            float t     = w0.x * r6inv;
            float eps   = w0.y;
            float cc    = w0.z;
            outE[OFF_EV + v0] = eps * (t * t - 2.0f * t);
            outE[OFF_EC + v0] = cc * rinv;
            float fs    = (12.0f * eps * t * (1.0f - t) * rinv - cc * r2inv) * keep;
            unsigned pck = __float_as_uint(w0.w);
            int b0 = (int)(pck & 0xffffu);
            int b1 = (int)(pck >> 16);
            lds_pk_add(fxy, b0, A.x * fs, A.y * fs);
            atomicAdd(&fz[b0], A.z * fs);
            lds_pk_add(fxy, b1, A.w * fs, B.x * fs);
            atomicAdd(&fz[b1], B.y * fs);
        }
        // --- v1 ---
        {
            float rinv  = __builtin_amdgcn_rcpf(rr.y);
            float r2inv = rinv * rinv;
            float r6inv = r2inv * r2inv * r2inv;
            float t     = w1.x * r6inv;
            float eps   = w1.y;
            float cc    = w1.z;
            outE[OFF_EV + v0 + 1] = eps * (t * t - 2.0f * t);
            outE[OFF_EC + v0 + 1] = cc * rinv;
            float fs    = (12.0f * eps * t * (1.0f - t) * rinv - cc * r2inv) * keep;
            unsigned pck = __float_as_uint(w1.w);
            int b0 = (int)(pck & 0xffffu);
            int b1 = (int)(pck >> 16);
            lds_pk_add(fxy, b0, B.z * fs, B.w * fs);
            atomicAdd(&fz[b0], C.x * fs);
            lds_pk_add(fxy, b1, C.y * fs, C.z * fs);
            atomicAdd(&fz[b1], C.w * fs);
        }
        w0 = w0n; w1 = w1n; rr = rrn; A = An; B = Bn; C = Cn;
    }
    asm volatile("" ::: "memory");
    __syncthreads();

    // flush LDS -> plane-layout partial (fully coalesced)
    for (int k = tid; k < N_ATOMS; k += VBLK) {
        unsigned u = fxy[k];
        h2 hv = __builtin_bit_cast(h2, u);
        mypart[0 * N_ATOMS + k] = (float)hv.x;
        mypart[1 * N_ATOMS + k] = (float)hv.y;
        mypart[2 * N_ATOMS + k] = fz[k];
    }
}

// ---------------------------------------------------------------------------
// Kernel 3: deterministic reduction of the NPART partials into Force.
__global__ __launch_bounds__(256) void reduce_kernel(
    const float* __restrict__ part,
    float* __restrict__ out)
{
    int t = blockIdx.x * 256 + threadIdx.x;
    if (t >= NS * N_ATOMS * 3) return;
    int s = t / (N_ATOMS * 3);
    int r = t - s * (N_ATOMS * 3);
    int comp = r % 3;
    int k = r / 3;
    const float* p = part + (size_t)s * NPART * (N_ATOMS * 3) + comp * N_ATOMS + k;
    float acc = 0.0f;
    #pragma unroll
    for (int c = 0; c < NPART; ++c) acc += p[(size_t)c * (N_ATOMS * 3)];
    out[(size_t)s * OUT_S + OFF_F + r] = acc;
}

// ---------------------------------------------------------------------------
extern "C" void kernel_launch(void* const* d_in, const int* in_sizes, int n_in,
                              void* d_out, int out_size, void* d_ws, size_t ws_size,
                              hipStream_t stream) {
    const float* lb  = (const float*)d_in[0];
    const float* th  = (const float*)d_in[1];
    const float* lv  = (const float*)d_in[2];
    const float* sc  = (const float*)d_in[3];
    const float* c2i = (const float*)d_in[4];
    const float* v14 = (const float*)d_in[5];
    const float* q14 = (const float*)d_in[6];
    const float* pb  = (const float*)d_in[7];
    const float* pa  = (const float*)d_in[8];
    const float* pv  = (const float*)d_in[9];
    const float* pc  = (const float*)d_in[10];
    const float* pt  = (const float*)d_in[11];
    const float* pim = (const float*)d_in[12];
    const float* dlb = (const float*)d_in[13];
    const float* dth = (const float*)d_in[14];
    const float* dlv = (const float*)d_in[15];
    const float* dtt = (const float*)d_in[16];
    const float* dc2 = (const float*)d_in[17];
    const int* nb    = (const int*)d_in[18];
    const int* bidx  = (const int*)d_in[19];
    const int* aidx  = (const int*)d_in[20];
    const int* nbi   = (const int*)d_in[21];
    const int* tidx  = (const int*)d_in[22];
    const int* iidx  = (const int*)d_in[23];
    float* out = (float*)d_out;
    float4* ws = (float4*)d_ws;
    float* part = (float*)d_ws + (size_t)NV * 4;   // after 6.4MB of params

    // 1) prep params + E_ub zero
    prep_kernel<<<(NV + 511) / 512, 512, 0, stream>>>(v14, q14, pv, pc, nb, nbi, ws, out);

    // 2) fused vdw+charge / bonded, partials to ws (no global atomics)
    {
        dim3 grid(NS, NPART);
        fused_kernel<<<grid, VBLK, 0, stream>>>(
            lv, dlv, ws, part, lb, th, sc, c2i, pb, pa, pt, pim,
            dlb, dth, dtt, dc2, bidx, aidx, tidx, iidx, out);
    }

    // 3) reduce partials into Force
    reduce_kernel<<<(NS * N_ATOMS * 3 + 255) / 256, 256, 0, stream>>>(part, out);
}

// Round 6
// 216.395 us; speedup vs baseline: 1.1425x; 1.1425x over previous
//
#include <hip/hip_runtime.h>

#define NS 16
#define N_ATOMS 2000
#define NB 2000
#define NA 4000
#define NV 400000
#define NT 6000
#define NI 1000

#define OUT_S 819001
#define OFF_EB 0
#define OFF_EA 2000
#define OFF_EUB 6000
#define OFF_EV 6001
#define OFF_EC 406001
#define OFF_ET 806001
#define OFF_EI 812001
#define OFF_F 813001

#define CHARGE_TENTH 1.8222615f

#define NPAIRS 200000            // NV/2
#define VBLK 256
#define GBATCH 4
#define ROUNDS 2
#define PPC (VBLK * GBATCH * ROUNDS)       // 2048 pairs per block
#define NCHUNKS ((NPAIRS + PPC - 1) / PPC) // 98
#define BBLKS 4
#define NBOND_TOT (NB + NA + NT + NI)      // 13000
#define BTPB ((NBOND_TOT + BBLKS - 1) / BBLKS)  // 3250

typedef __fp16 h2 __attribute__((ext_vector_type(2)));

// ---------------------------------------------------------------------------
// Kernel 1: zero Force + E_ub, and per-v vdw/charge param precompute.
__global__ __launch_bounds__(512) void prep_kernel(
    const float* __restrict__ v14,
    const float* __restrict__ q14,
    const float* __restrict__ pv,
    const float* __restrict__ pc,
    const int*   __restrict__ nb,
    const int*   __restrict__ nbi,
    float4* __restrict__ ws,
    float* __restrict__ out)
{
    int idx = blockIdx.x * blockDim.x + threadIdx.x;
    if (idx < NS)
        out[(size_t)idx * OUT_S + OFF_EUB] = 0.0f;
    if (idx < NS * N_ATOMS * 3) {
        int s = idx / (N_ATOMS * 3);
        int r = idx - s * (N_ATOMS * 3);
        out[(size_t)s * OUT_S + OFF_F + r] = 0.0f;
    }
    if (idx < NV) {
        int v = idx;
        int i = nb[v];
        int j = nb[NV + v];
        float2 pvi = ((const float2*)pv)[i];
        float2 pvj = ((const float2*)pv)[j];
        float sigma = pvi.x + pvj.x;
        float sig2  = sigma * sigma;
        float sig6  = sig2 * sig2 * sig2;
        float eps   = pvi.y * pvj.y * 0.01f * v14[v];
        float cc    = (CHARGE_TENTH * CHARGE_TENTH) * pc[i] * pc[j] * q14[v];
        int2 aa = ((const int2*)nbi)[v];
        unsigned int packed = (unsigned int)aa.x | ((unsigned int)aa.y << 16);
        float4 w;
        w.x = sig6; w.y = eps; w.z = cc; w.w = __uint_as_float(packed);
        ws[v] = w;
    }
}

// ---------------------------------------------------------------------------
__device__ __forceinline__ void lds_pk_add(unsigned* base, int idx, float x, float y) {
    h2 ph = __builtin_amdgcn_cvt_pkrtz(x, y);
    unsigned pk = __builtin_bit_cast(unsigned, ph);
    unsigned addr = (unsigned)(uintptr_t)(&base[idx]);
    asm volatile("ds_pk_add_f16 %0, %1" : : "v"(addr), "v"(pk));
}

// ---------------------------------------------------------------------------
// Kernel 2: fat kernel. y < NCHUNKS: vdw+charge chunk (2048 pairs, G=4-batched
// loads pinned ahead of compute for MLP); y >= NCHUNKS: bonded quarter.
// Both paths accumulate into 16KB LDS (pk-f16 xy + f32 z), flush via global
// atomics.
__global__ __launch_bounds__(VBLK, 4) void fused_kernel(
    const float*  __restrict__ lv,
    const float*  __restrict__ dlv,
    const float4* __restrict__ ws,
    const float* __restrict__ lb,
    const float* __restrict__ th,
    const float* __restrict__ sc,
    const float* __restrict__ c2i,
    const float* __restrict__ pb,
    const float* __restrict__ pa,
    const float* __restrict__ pt,
    const float* __restrict__ pim,
    const float* __restrict__ dlb,
    const float* __restrict__ dth,
    const float* __restrict__ dtt,
    const float* __restrict__ dc2,
    const int*   __restrict__ bidx,
    const int*   __restrict__ aidx,
    const int*   __restrict__ tidx,
    const int*   __restrict__ iidx,
    float* __restrict__ out)
{
    __shared__ unsigned fxy[N_ATOMS];   // packed f16 (x,y)
    __shared__ float    fz[N_ATOMS];    // f32 z
    int tid = threadIdx.x;
    int s   = blockIdx.x;
    int y   = blockIdx.y;
    float* outE = out + (size_t)s * OUT_S;
    float* F = outE + OFF_F;

    for (int k = tid; k < N_ATOMS; k += VBLK) { fxy[k] = 0u; fz[k] = 0.0f; }
    __syncthreads();

    if (y < NCHUNKS) {
        // ---------------- vdw + charge ----------------
        const int pbase = y * PPC;
        const int PLAST = NPAIRS - 1;
        const float2* lvp   = (const float2*)(lv + (size_t)s * NV);
        const float4* dbase = (const float4*)(dlv + (size_t)s * NV * 6);

        for (int rnd = 0; rnd < ROUNDS; ++rnd) {
            float4 w0[GBATCH], w1[GBATCH], A[GBATCH], B[GBATCH], C[GBATCH];
            float2 rr[GBATCH];
            int praw[GBATCH];
            // ---- issue ALL loads for this round ----
            #pragma unroll
            for (int g = 0; g < GBATCH; ++g) {
                praw[g] = pbase + (rnd * GBATCH + g) * VBLK + tid;
                int p = (praw[g] > PLAST) ? PLAST : praw[g];
                w0[g] = ws[2 * p];
                w1[g] = ws[2 * p + 1];
                rr[g] = lvp[p];
                A[g] = dbase[3 * (size_t)p];
                B[g] = dbase[3 * (size_t)p + 1];
                C[g] = dbase[3 * (size_t)p + 2];
            }
            // pin the loads above this point
            asm volatile("" ::: "memory");
            // ---- compute ----
            #pragma unroll
            for (int g = 0; g < GBATCH; ++g) {
                float keep = (praw[g] < NPAIRS) ? 1.0f : 0.0f;
                int p = (praw[g] > PLAST) ? PLAST : praw[g];
                int v0 = 2 * p;
                {
                    float rinv  = __builtin_amdgcn_rcpf(rr[g].x);
                    float r2inv = rinv * rinv;
                    float r6inv = r2inv * r2inv * r2inv;
                    float t     = w0[g].x * r6inv;
                    float eps   = w0[g].y;
                    float cc    = w0[g].z;
                    outE[OFF_EV + v0] = eps * (t * t - 2.0f * t);
                    outE[OFF_EC + v0] = cc * rinv;
                    float fs = (12.0f * eps * t * (1.0f - t) * rinv - cc * r2inv) * keep;
                    unsigned pck = __float_as_uint(w0[g].w);
                    int b0 = (int)(pck & 0xffffu);
                    int b1 = (int)(pck >> 16);
                    lds_pk_add(fxy, b0, A[g].x * fs, A[g].y * fs);
                    atomicAdd(&fz[b0], A[g].z * fs);
                    lds_pk_add(fxy, b1, A[g].w * fs, B[g].x * fs);
                    atomicAdd(&fz[b1], B[g].y * fs);
                }
                {
                    float rinv  = __builtin_amdgcn_rcpf(rr[g].y);
                    float r2inv = rinv * rinv;
                    float r6inv = r2inv * r2inv * r2inv;
                    float t     = w1[g].x * r6inv;
                    float eps   = w1[g].y;
                    float cc    = w1[g].z;
                    outE[OFF_EV + v0 + 1] = eps * (t * t - 2.0f * t);
                    outE[OFF_EC + v0 + 1] = cc * rinv;
                    float fs = (12.0f * eps * t * (1.0f - t) * rinv - cc * r2inv) * keep;
                    unsigned pck = __float_as_uint(w1[g].w);
                    int b0 = (int)(pck & 0xffffu);
                    int b1 = (int)(pck >> 16);
                    lds_pk_add(fxy, b0, B[g].z * fs, B[g].w * fs);
                    atomicAdd(&fz[b0], C[g].x * fs);
                    lds_pk_add(fxy, b1, C[g].y * fs, C[g].z * fs);
                    atomicAdd(&fz[b1], C[g].w * fs);
                }
            }
        }
    } else {
        // ---------------- bonded quarter ----------------
        int t0 = (y - NCHUNKS) * BTPB;
        int tend = t0 + BTPB; if (tend > NBOND_TOT) tend = NBOND_TOT;
        for (int t = t0 + tid; t < tend; t += VBLK) {
            if (t < NB) {
                int b = t;
                float2 p = ((const float2*)pb)[b];
                float K  = p.x * 100.0f;
                float d  = lb[s * NB + b] - p.y;
                outE[OFF_EB + b] = K * d * d;
                float g = 2.0f * K * d;
                const float2* dd = (const float2*)(dlb + ((size_t)s * NB + b) * 6);
                float2 d0 = dd[0], d1 = dd[1], d2 = dd[2];
                int a0 = bidx[2 * b], a1 = bidx[2 * b + 1];
                lds_pk_add(fxy, a0, d0.x * g, d0.y * g);
                atomicAdd(&fz[a0], d1.x * g);
                lds_pk_add(fxy, a1, d1.y * g, d2.x * g);
                atomicAdd(&fz[a1], d2.y * g);
            } else if (t < NB + NA) {
                int a = t - NB;
                float2 p = ((const float2*)pa)[a];
                float Ka  = p.x * 10.0f;
                float da  = th[s * NA + a] - p.y * 0.31415926535f;
                outE[OFF_EA + a] = Ka * da * da;
                float g = 2.0f * Ka * da;
                const float* dd = dth + ((size_t)s * NA + a) * 9;
                int a0 = aidx[3 * a], a1 = aidx[3 * a + 1], a2 = aidx[3 * a + 2];
                lds_pk_add(fxy, a0, dd[0] * g, dd[1] * g);
                atomicAdd(&fz[a0], dd[2] * g);
                lds_pk_add(fxy, a1, dd[3] * g, dd[4] * g);
                atomicAdd(&fz[a1], dd[5] * g);
                lds_pk_add(fxy, a2, dd[6] * g, dd[7] * g);
                atomicAdd(&fz[a2], dd[8] * g);
            } else if (t < NB + NA + NT) {
                int tt = t - (NB + NA);
                const float4* s8 = (const float4*)(sc + ((size_t)s * NT + tt) * 8);
                float4 sA = s8[0], sB = s8[1];
                float4 p4 = ((const float4*)pt)[tt];
                float E  = sA.y * p4.x + sA.w * p4.y + sB.y * p4.z + sB.w * p4.w;
                float Sf = sA.x * p4.x + sA.z * p4.y * 2.0f + sB.x * p4.z * 3.0f + sB.z * p4.w * 4.0f;
                outE[OFF_ET + tt] = E;
                float g = -Sf;
                const float4* dd = (const float4*)(dtt + ((size_t)s * NT + tt) * 12);
                float4 dA = dd[0], dB = dd[1], dC = dd[2];
                int a0 = tidx[4 * tt], a1 = tidx[4 * tt + 1],
                    a2 = tidx[4 * tt + 2], a3 = tidx[4 * tt + 3];
                lds_pk_add(fxy, a0, dA.x * g, dA.y * g);
                atomicAdd(&fz[a0], dA.z * g);
                lds_pk_add(fxy, a1, dA.w * g, dB.x * g);
                atomicAdd(&fz[a1], dB.y * g);
                lds_pk_add(fxy, a2, dB.z * g, dB.w * g);
                atomicAdd(&fz[a2], dC.x * g);
                lds_pk_add(fxy, a3, dC.y * g, dC.z * g);
                atomicAdd(&fz[a3], dC.w * g);
            } else {
                int ii = t - (NB + NA + NT);
                float ki = pim[ii];
                outE[OFF_EI + ii] = ki * (1.0f - c2i[s * NI + ii]);
                float g = -ki;
                const float4* dd = (const float4*)(dc2 + ((size_t)s * NI + ii) * 12);
                float4 dA = dd[0], dB = dd[1], dC = dd[2];
                int a0 = iidx[4 * ii], a1 = iidx[4 * ii + 1],
                    a2 = iidx[4 * ii + 2], a3 = iidx[4 * ii + 3];
                lds_pk_add(fxy, a0, dA.x * g, dA.y * g);
                atomicAdd(&fz[a0], dA.z * g);
                lds_pk_add(fxy, a1, dA.w * g, dB.x * g);
                atomicAdd(&fz[a1], dB.y * g);
                lds_pk_add(fxy, a2, dB.z * g, dB.w * g);
                atomicAdd(&fz[a2], dC.x * g);
                lds_pk_add(fxy, a3, dC.y * g, dC.z * g);
                atomicAdd(&fz[a3], dC.w * g);
            }
        }
    }

    asm volatile("" ::: "memory");
    __syncthreads();

    // flush LDS -> global Force via atomics
    for (int k = tid; k < N_ATOMS; k += VBLK) {
        unsigned u = fxy[k];
        h2 hv = __builtin_bit_cast(h2, u);
        float x = (float)hv.x;
        float yv = (float)hv.y;
        float z = fz[k];
        if (x != 0.0f) atomicAdd(&F[3 * k + 0], x);
        if (yv != 0.0f) atomicAdd(&F[3 * k + 1], yv);
        if (z != 0.0f) atomicAdd(&F[3 * k + 2], z);
    }
}

// ---------------------------------------------------------------------------
extern "C" void kernel_launch(void* const* d_in, const int* in_sizes, int n_in,
                              void* d_out, int out_size, void* d_ws, size_t ws_size,
                              hipStream_t stream) {
    const float* lb  = (const float*)d_in[0];
    const float* th  = (const float*)d_in[1];
    const float* lv  = (const float*)d_in[2];
    const float* sc  = (const float*)d_in[3];
    const float* c2i = (const float*)d_in[4];
    const float* v14 = (const float*)d_in[5];
    const float* q14 = (const float*)d_in[6];
    const float* pb  = (const float*)d_in[7];
    const float* pa  = (const float*)d_in[8];
    const float* pv  = (const float*)d_in[9];
    const float* pc  = (const float*)d_in[10];
    const float* pt  = (const float*)d_in[11];
    const float* pim = (const float*)d_in[12];
    const float* dlb = (const float*)d_in[13];
    const float* dth = (const float*)d_in[14];
    const float* dlv = (const float*)d_in[15];
    const float* dtt = (const float*)d_in[16];
    const float* dc2 = (const float*)d_in[17];
    const int* nb    = (const int*)d_in[18];
    const int* bidx  = (const int*)d_in[19];
    const int* aidx  = (const int*)d_in[20];
    const int* nbi   = (const int*)d_in[21];
    const int* tidx  = (const int*)d_in[22];
    const int* iidx  = (const int*)d_in[23];
    float* out = (float*)d_out;
    float4* ws = (float4*)d_ws;

    // 1) prep params + zero F/E_ub
    prep_kernel<<<(NV + 511) / 512, 512, 0, stream>>>(v14, q14, pv, pc, nb, nbi, ws, out);

    // 2) fused vdw+charge / bonded
    {
        dim3 grid(NS, NCHUNKS + BBLKS);
        fused_kernel<<<grid, VBLK, 0, stream>>>(
            lv, dlv, ws, lb, th, sc, c2i, pb, pa, pt, pim,
            dlb, dth, dtt, dc2, bidx, aidx, tidx, iidx, out);
    }
}

// Round 7
// 209.964 us; speedup vs baseline: 1.1775x; 1.0306x over previous
//
#include <hip/hip_runtime.h>

#define NS 16
#define N_ATOMS 2000
#define NB 2000
#define NA 4000
#define NV 400000
#define NT 6000
#define NI 1000

#define OUT_S 819001
#define OFF_EB 0
#define OFF_EA 2000
#define OFF_EUB 6000
#define OFF_EV 6001
#define OFF_EC 406001
#define OFF_ET 806001
#define OFF_EI 812001
#define OFF_F 813001

#define CHARGE_TENTH 1.8222615f

#define NPAIRS 200000            // NV/2
#define F4LAST (NPAIRS * 3 - 1)  // last valid float4 index in dlv (per sample)
#define VBLK 256
#define NW 4                     // waves per block
#define ROUNDS 8
#define PPC (NW * 64 * ROUNDS)   // 2048 pairs per block
#define NCHUNKS ((NPAIRS + PPC - 1) / PPC)   // 98
#define BBLKS 4
#define NBOND_TOT (NB + NA + NT + NI)        // 13000
#define BTPB ((NBOND_TOT + BBLKS - 1) / BBLKS)   // 3250

typedef __fp16 h2 __attribute__((ext_vector_type(2)));

// ---------------------------------------------------------------------------
// Kernel 1: zero Force + E_ub; per-pair param precompute into TWO pair-major
// planes (wsA = params of v=2p, wsB = params of v=2p+1) so the main kernel's
// param loads are unit-stride.
__global__ __launch_bounds__(512) void prep_kernel(
    const float* __restrict__ v14,
    const float* __restrict__ q14,
    const float* __restrict__ pv,
    const float* __restrict__ pc,
    const int*   __restrict__ nb,
    const int*   __restrict__ nbi,
    float4* __restrict__ wsA,
    float4* __restrict__ wsB,
    float* __restrict__ out)
{
    int idx = blockIdx.x * blockDim.x + threadIdx.x;
    if (idx < NS)
        out[(size_t)idx * OUT_S + OFF_EUB] = 0.0f;
    if (idx < NS * N_ATOMS * 3) {
        int s = idx / (N_ATOMS * 3);
        int r = idx - s * (N_ATOMS * 3);
        out[(size_t)s * OUT_S + OFF_F + r] = 0.0f;
    }
    if (idx < NV) {
        int v = idx;
        int i = nb[v];
        int j = nb[NV + v];
        float2 pvi = ((const float2*)pv)[i];
        float2 pvj = ((const float2*)pv)[j];
        float sigma = pvi.x + pvj.x;
        float sig2  = sigma * sigma;
        float sig6  = sig2 * sig2 * sig2;
        float eps   = pvi.y * pvj.y * 0.01f * v14[v];
        float cc    = (CHARGE_TENTH * CHARGE_TENTH) * pc[i] * pc[j] * q14[v];
        int2 aa = ((const int2*)nbi)[v];
        unsigned int packed = (unsigned int)aa.x | ((unsigned int)aa.y << 16);
        float4 w;
        w.x = sig6; w.y = eps; w.z = cc; w.w = __uint_as_float(packed);
        if (v & 1) wsB[v >> 1] = w;
        else       wsA[v >> 1] = w;
    }
}

// ---------------------------------------------------------------------------
__device__ __forceinline__ void lds_pk_add(unsigned* base, int idx, float x, float y) {
    h2 ph = __builtin_amdgcn_cvt_pkrtz(x, y);
    unsigned pk = __builtin_bit_cast(unsigned, ph);
    unsigned addr = (unsigned)(uintptr_t)(&base[idx]);
    asm volatile("ds_pk_add_f16 %0, %1" : : "v"(addr), "v"(pk));
}

// ---------------------------------------------------------------------------
// Kernel 2: fat kernel. y < NCHUNKS: vdw+charge (all VMEM unit-stride; dlv
// staged per-wave through LDS); y >= NCHUNKS: bonded quarter. Both accumulate
// into 16 KB LDS (pk-f16 xy + f32 z), flush via global atomics.
__global__ __launch_bounds__(VBLK, 4) void fused_kernel(
    const float*  __restrict__ lv,
    const float*  __restrict__ dlv,
    const float4* __restrict__ wsA,
    const float4* __restrict__ wsB,
    const float* __restrict__ lb,
    const float* __restrict__ th,
    const float* __restrict__ sc,
    const float* __restrict__ c2i,
    const float* __restrict__ pb,
    const float* __restrict__ pa,
    const float* __restrict__ pt,
    const float* __restrict__ pim,
    const float* __restrict__ dlb,
    const float* __restrict__ dth,
    const float* __restrict__ dtt,
    const float* __restrict__ dc2,
    const int*   __restrict__ bidx,
    const int*   __restrict__ aidx,
    const int*   __restrict__ tidx,
    const int*   __restrict__ iidx,
    float* __restrict__ out)
{
    __shared__ unsigned fxy[N_ATOMS];        // packed f16 (x,y)
    __shared__ float    fz[N_ATOMS];         // f32 z
    __shared__ float4   stage[NW][192];      // per-wave dlv tile (3 KB each)

    int tid  = threadIdx.x;
    int lane = tid & 63;
    int w    = tid >> 6;
    int s    = blockIdx.x;
    int y    = blockIdx.y;
    float* outE = out + (size_t)s * OUT_S;
    float* F = outE + OFF_F;

    for (int k = tid; k < N_ATOMS; k += VBLK) { fxy[k] = 0u; fz[k] = 0.0f; }
    __syncthreads();

    if (y < NCHUNKS) {
        // ---------------- vdw + charge ----------------
        const int pbase = y * PPC;
        const int PLAST = NPAIRS - 1;
        const float2* lvp   = (const float2*)(lv + (size_t)s * NV);
        const float4* dfl   = (const float4*)(dlv + (size_t)s * NV * 6);
        float4* st = stage[w];

        for (int it = 0; it < ROUNDS; ++it) {
            int wb   = pbase + (it * NW + w) * 64;   // wave's pair base
            int praw = wb + lane;
            int p    = (praw > PLAST) ? PLAST : praw;

            // unit-stride loads
            float2 rr = lvp[p];
            float4 wA = wsA[p];
            float4 wB = wsB[p];

            // dlv: 3 coalesced float4 loads -> LDS stage -> per-pair read
            size_t fb = (size_t)wb * 3;
            size_t i0 = fb + lane;        if (i0 > F4LAST) i0 = F4LAST;
            size_t i1 = fb + 64 + lane;   if (i1 > F4LAST) i1 = F4LAST;
            size_t i2 = fb + 128 + lane;  if (i2 > F4LAST) i2 = F4LAST;
            float4 t0 = dfl[i0];
            float4 t1 = dfl[i1];
            float4 t2 = dfl[i2];
            st[lane]       = t0;
            st[64 + lane]  = t1;
            st[128 + lane] = t2;
            float4 A = st[3 * lane];
            float4 B = st[3 * lane + 1];
            float4 C = st[3 * lane + 2];

            float keep = (praw < NPAIRS) ? 1.0f : 0.0f;
            bool  livestore = (praw < NPAIRS);
            int v0 = 2 * p;
            {
                float rinv  = __builtin_amdgcn_rcpf(rr.x);
                float r2inv = rinv * rinv;
                float r6inv = r2inv * r2inv * r2inv;
                float t     = wA.x * r6inv;
                float eps   = wA.y;
                float cc    = wA.z;
                if (livestore) {
                    outE[OFF_EV + v0] = eps * (t * t - 2.0f * t);
                    outE[OFF_EC + v0] = cc * rinv;
                }
                float fs = (12.0f * eps * t * (1.0f - t) * rinv - cc * r2inv) * keep;
                unsigned pck = __float_as_uint(wA.w);
                int b0 = (int)(pck & 0xffffu);
                int b1 = (int)(pck >> 16);
                lds_pk_add(fxy, b0, A.x * fs, A.y * fs);
                atomicAdd(&fz[b0], A.z * fs);
                lds_pk_add(fxy, b1, A.w * fs, B.x * fs);
                atomicAdd(&fz[b1], B.y * fs);
            }
            {
                float rinv  = __builtin_amdgcn_rcpf(rr.y);
                float r2inv = rinv * rinv;
                float r6inv = r2inv * r2inv * r2inv;
                float t     = wB.x * r6inv;
                float eps   = wB.y;
                float cc    = wB.z;
                if (livestore) {
                    outE[OFF_EV + v0 + 1] = eps * (t * t - 2.0f * t);
                    outE[OFF_EC + v0 + 1] = cc * rinv;
                }
                float fs = (12.0f * eps * t * (1.0f - t) * rinv - cc * r2inv) * keep;
                unsigned pck = __float_as_uint(wB.w);
                int b0 = (int)(pck & 0xffffu);
                int b1 = (int)(pck >> 16);
                lds_pk_add(fxy, b0, B.z * fs, B.w * fs);
                atomicAdd(&fz[b0], C.x * fs);
                lds_pk_add(fxy, b1, C.y * fs, C.z * fs);
                atomicAdd(&fz[b1], C.w * fs);
            }
        }
    } else {
        // ---------------- bonded quarter ----------------
        int t0 = (y - NCHUNKS) * BTPB;
        int tend = t0 + BTPB; if (tend > NBOND_TOT) tend = NBOND_TOT;
        for (int t = t0 + tid; t < tend; t += VBLK) {
            if (t < NB) {
                int b = t;
                float2 p = ((const float2*)pb)[b];
                float K  = p.x * 100.0f;
                float d  = lb[s * NB + b] - p.y;
                outE[OFF_EB + b] = K * d * d;
                float g = 2.0f * K * d;
                const float2* dd = (const float2*)(dlb + ((size_t)s * NB + b) * 6);
                float2 d0 = dd[0], d1 = dd[1], d2 = dd[2];
                int a0 = bidx[2 * b], a1 = bidx[2 * b + 1];
                lds_pk_add(fxy, a0, d0.x * g, d0.y * g);
                atomicAdd(&fz[a0], d1.x * g);
                lds_pk_add(fxy, a1, d1.y * g, d2.x * g);
                atomicAdd(&fz[a1], d2.y * g);
            } else if (t < NB + NA) {
                int a = t - NB;
                float2 p = ((const float2*)pa)[a];
                float Ka  = p.x * 10.0f;
                float da  = th[s * NA + a] - p.y * 0.31415926535f;
                outE[OFF_EA + a] = Ka * da * da;
                float g = 2.0f * Ka * da;
                const float* dd = dth + ((size_t)s * NA + a) * 9;
                int a0 = aidx[3 * a], a1 = aidx[3 * a + 1], a2 = aidx[3 * a + 2];
                lds_pk_add(fxy, a0, dd[0] * g, dd[1] * g);
                atomicAdd(&fz[a0], dd[2] * g);
                lds_pk_add(fxy, a1, dd[3] * g, dd[4] * g);
                atomicAdd(&fz[a1], dd[5] * g);
                lds_pk_add(fxy, a2, dd[6] * g, dd[7] * g);
                atomicAdd(&fz[a2], dd[8] * g);
            } else if (t < NB + NA + NT) {
                int tt = t - (NB + NA);
                const float4* s8 = (const float4*)(sc + ((size_t)s * NT + tt) * 8);
                float4 sA = s8[0], sB = s8[1];
                float4 p4 = ((const float4*)pt)[tt];
                float E  = sA.y * p4.x + sA.w * p4.y + sB.y * p4.z + sB.w * p4.w;
                float Sf = sA.x * p4.x + sA.z * p4.y * 2.0f + sB.x * p4.z * 3.0f + sB.z * p4.w * 4.0f;
                outE[OFF_ET + tt] = E;
                float g = -Sf;
                const float4* dd = (const float4*)(dtt + ((size_t)s * NT + tt) * 12);
                float4 dA = dd[0], dB = dd[1], dC = dd[2];
                int a0 = tidx[4 * tt], a1 = tidx[4 * tt + 1],
                    a2 = tidx[4 * tt + 2], a3 = tidx[4 * tt + 3];
                lds_pk_add(fxy, a0, dA.x * g, dA.y * g);
                atomicAdd(&fz[a0], dA.z * g);
                lds_pk_add(fxy, a1, dA.w * g, dB.x * g);
                atomicAdd(&fz[a1], dB.y * g);
                lds_pk_add(fxy, a2, dB.z * g, dB.w * g);
                atomicAdd(&fz[a2], dC.x * g);
                lds_pk_add(fxy, a3, dC.y * g, dC.z * g);
                atomicAdd(&fz[a3], dC.w * g);
            } else {
                int ii = t - (NB + NA + NT);
                float ki = pim[ii];
                outE[OFF_EI + ii] = ki * (1.0f - c2i[s * NI + ii]);
                float g = -ki;
                const float4* dd = (const float4*)(dc2 + ((size_t)s * NI + ii) * 12);
                float4 dA = dd[0], dB = dd[1], dC = dd[2];
                int a0 = iidx[4 * ii], a1 = iidx[4 * ii + 1],
                    a2 = iidx[4 * ii + 2], a3 = iidx[4 * ii + 3];
                lds_pk_add(fxy, a0, dA.x * g, dA.y * g);
                atomicAdd(&fz[a0], dA.z * g);
                lds_pk_add(fxy, a1, dA.w * g, dB.x * g);
                atomicAdd(&fz[a1], dB.y * g);
                lds_pk_add(fxy, a2, dB.z * g, dB.w * g);
                atomicAdd(&fz[a2], dC.x * g);
                lds_pk_add(fxy, a3, dC.y * g, dC.z * g);
                atomicAdd(&fz[a3], dC.w * g);
            }
        }
    }

    // make the asm DS ops visible + drained before the barrier
    asm volatile("s_waitcnt lgkmcnt(0)" ::: "memory");
    __syncthreads();

    // flush LDS -> global Force via atomics
    for (int k = tid; k < N_ATOMS; k += VBLK) {
        unsigned u = fxy[k];
        h2 hv = __builtin_bit_cast(h2, u);
        float x  = (float)hv.x;
        float yv = (float)hv.y;
        float z  = fz[k];
        if (x  != 0.0f) atomicAdd(&F[3 * k + 0], x);
        if (yv != 0.0f) atomicAdd(&F[3 * k + 1], yv);
        if (z  != 0.0f) atomicAdd(&F[3 * k + 2], z);
    }
}

// ---------------------------------------------------------------------------
extern "C" void kernel_launch(void* const* d_in, const int* in_sizes, int n_in,
                              void* d_out, int out_size, void* d_ws, size_t ws_size,
                              hipStream_t stream) {
    const float* lb  = (const float*)d_in[0];
    const float* th  = (const float*)d_in[1];
    const float* lv  = (const float*)d_in[2];
    const float* sc  = (const float*)d_in[3];
    const float* c2i = (const float*)d_in[4];
    const float* v14 = (const float*)d_in[5];
    const float* q14 = (const float*)d_in[6];
    const float* pb  = (const float*)d_in[7];
    const float* pa  = (const float*)d_in[8];
    const float* pv  = (const float*)d_in[9];
    const float* pc  = (const float*)d_in[10];
    const float* pt  = (const float*)d_in[11];
    const float* pim = (const float*)d_in[12];
    const float* dlb = (const float*)d_in[13];
    const float* dth = (const float*)d_in[14];
    const float* dlv = (const float*)d_in[15];
    const float* dtt = (const float*)d_in[16];
    const float* dc2 = (const float*)d_in[17];
    const int* nb    = (const int*)d_in[18];
    const int* bidx  = (const int*)d_in[19];
    const int* aidx  = (const int*)d_in[20];
    const int* nbi   = (const int*)d_in[21];
    const int* tidx  = (const int*)d_in[22];
    const int* iidx  = (const int*)d_in[23];
    float* out = (float*)d_out;
    float4* wsA = (float4*)d_ws;
    float4* wsB = wsA + NPAIRS;

    // 1) prep params (pair-major planes) + zero F/E_ub
    prep_kernel<<<(NV + 511) / 512, 512, 0, stream>>>(v14, q14, pv, pc, nb, nbi, wsA, wsB, out);

    // 2) fused vdw+charge / bonded
    {
        dim3 grid(NS, NCHUNKS + BBLKS);
        fused_kernel<<<grid, VBLK, 0, stream>>>(
            lv, dlv, wsA, wsB, lb, th, sc, c2i, pb, pa, pt, pim,
            dlb, dth, dtt, dc2, bidx, aidx, tidx, iidx, out);
    }
}